// Round 1
// baseline (445.645 us; speedup 1.0000x reference)
//
#include <hip/hip_runtime.h>
#include <hip/hip_bf16.h>
#include <stdint.h>

#define H_DIM 4096
#define NH 32
#define HD 128
#define SEQ 1024
#define CTX 4096
#define KVL (CTX + SEQ)      // 5120
#define W3H (3 * H_DIM)      // 12288
#define ATTN_SCALE 0.08838834764831845f

typedef short short8 __attribute__((ext_vector_type(8)));
typedef float f32x4 __attribute__((ext_vector_type(4)));

// async global->LDS, 16B per lane; LDS dest must be wave-uniform base (HW adds lane*16)
#define GLOAD_LDS16(g, l)                                             \
  __builtin_amdgcn_global_load_lds(                                   \
      (const __attribute__((address_space(1))) void*)(g),             \
      (__attribute__((address_space(3))) void*)(l), 16, 0, 0)

__device__ __forceinline__ unsigned short f2b(float f) {
  union { float f; unsigned u; } v; v.f = f;
  return (unsigned short)((v.u + 0x7FFFu + ((v.u >> 16) & 1u)) >> 16);
}

// ---------------- f32 -> bf16 convert (vectorized) ----------------
__global__ void k_cvt(const float* __restrict__ s, unsigned short* __restrict__ d, int n4) {
  int i = blockIdx.x * blockDim.x + threadIdx.x;
  if (i >= n4) return;
  float4 v = reinterpret_cast<const float4*>(s)[i];
  ushort4 o;
  o.x = f2b(v.x); o.y = f2b(v.y); o.z = f2b(v.z); o.w = f2b(v.w);
  reinterpret_cast<ushort4*>(d)[i] = o;
}

// ---------------- QKV GEMM: C[m][n] = sum_k A[m][k]*B[n][k] ----------------
// A = Xb [SEQ][H_DIM] bf16, B = Wb [W3H][H_DIM] bf16, C = QKVb [SEQ][W3H] bf16
#define BM 128
#define BN 128
#define BK 64
__global__ __launch_bounds__(256, 2) void k_gemm_qkv(
    const unsigned short* __restrict__ A,
    const unsigned short* __restrict__ B,
    unsigned short* __restrict__ C) {
  __shared__ unsigned short As[BM * BK];
  __shared__ unsigned short Bs[BN * BK];
  const int tid = threadIdx.x;
  const int lane = tid & 63;
  const int wid = tid >> 6;
  const int bn = blockIdx.x, bm = blockIdx.y;
  const int wr = wid >> 1, wc = wid & 1;

  f32x4 acc[4][4] = {};

  const int lrow = lane >> 3;       // row within an 8-row staging chunk
  const int lcol = (lane & 7) * 8;  // element col within row (16B granule)
  const unsigned short* ga = A + (size_t)(bm * BM + wid * 32 + lrow) * H_DIM + lcol;
  const unsigned short* gb = B + (size_t)(bn * BN + wid * 32 + lrow) * H_DIM + lcol;

  for (int kt = 0; kt < H_DIM / BK; ++kt) {
    __syncthreads();  // all waves done reading previous tile
    const unsigned short* gak = ga + kt * BK;
    const unsigned short* gbk = gb + kt * BK;
#pragma unroll
    for (int i = 0; i < 4; ++i) {
      GLOAD_LDS16(gak + i * 8 * H_DIM, As + (wid * 4 + i) * 512);
      GLOAD_LDS16(gbk + i * 8 * H_DIM, Bs + (wid * 4 + i) * 512);
    }
    __syncthreads();  // compiler drains vmcnt before barrier
#pragma unroll
    for (int kk = 0; kk < 2; ++kk) {
      short8 af[4], bfr[4];
#pragma unroll
      for (int m = 0; m < 4; ++m)
        af[m] = *reinterpret_cast<const short8*>(
            As + (wr * 64 + m * 16 + (lane & 15)) * BK + kk * 32 + (lane >> 4) * 8);
#pragma unroll
      for (int n = 0; n < 4; ++n)
        bfr[n] = *reinterpret_cast<const short8*>(
            Bs + (wc * 64 + n * 16 + (lane & 15)) * BK + kk * 32 + (lane >> 4) * 8);
#pragma unroll
      for (int m = 0; m < 4; ++m)
#pragma unroll
        for (int n = 0; n < 4; ++n)
          acc[m][n] = __builtin_amdgcn_mfma_f32_16x16x32_bf16(af[m], bfr[n], acc[m][n], 0, 0, 0);
    }
  }
  const int r0 = bm * BM + wr * 64 + (lane >> 4) * 4;
  const int c0 = bn * BN + wc * 64 + (lane & 15);
#pragma unroll
  for (int m = 0; m < 4; ++m)
#pragma unroll
    for (int n = 0; n < 4; ++n)
#pragma unroll
      for (int r = 0; r < 4; ++r)
        C[(size_t)(r0 + m * 16 + r) * W3H + c0 + n * 16] = f2b(acc[m][n][r]);
}

// ---------------- build Kb[h][kv][d] bf16 from cache_K(f32) + QKV(k section) ----------------
__global__ void k_build_k(const float* __restrict__ cK, const unsigned short* __restrict__ QKV,
                          unsigned short* __restrict__ Kb) {
  int idx = (blockIdx.x * 256 + threadIdx.x) * 4;
  if (idx >= NH * KVL * HD) return;
  int h = idx / (KVL * HD);
  int rem = idx % (KVL * HD);
  int kv = rem / HD;
  int d = rem % HD;
  ushort4 o;
  if (kv < CTX) {
    float4 v = *reinterpret_cast<const float4*>(cK + ((size_t)kv * NH + h) * HD + d);
    o.x = f2b(v.x); o.y = f2b(v.y); o.z = f2b(v.z); o.w = f2b(v.w);
  } else {
    o = *reinterpret_cast<const ushort4*>(QKV + (size_t)(kv - CTX) * W3H + H_DIM + h * HD + d);
  }
  *reinterpret_cast<ushort4*>(Kb + idx) = o;
}

// ---------------- build Vt[h][d][kv] bf16 (transposed) ----------------
__global__ void k_build_vt(const float* __restrict__ cV, const unsigned short* __restrict__ QKV,
                           unsigned short* __restrict__ Vt) {
  __shared__ unsigned short T[HD][66];
  const int h = blockIdx.y;
  const int kt = blockIdx.x;  // 80 tiles of 64 kv
  const int t = threadIdx.x;
#pragma unroll
  for (int e = 0; e < 8; ++e) {
    int idx = (t + e * 256) * 4;
    int kvl = idx >> 7;
    int d = idx & 127;
    int kv = kt * 64 + kvl;
    unsigned short a, b, c, w;
    if (kv < CTX) {
      float4 v = *reinterpret_cast<const float4*>(cV + ((size_t)kv * NH + h) * HD + d);
      a = f2b(v.x); b = f2b(v.y); c = f2b(v.z); w = f2b(v.w);
    } else {
      ushort4 u = *reinterpret_cast<const ushort4*>(QKV + (size_t)(kv - CTX) * W3H + 2 * H_DIM + h * HD + d);
      a = u.x; b = u.y; c = u.z; w = u.w;
    }
    T[d][kvl] = a; T[d + 1][kvl] = b; T[d + 2][kvl] = c; T[d + 3][kvl] = w;
  }
  __syncthreads();
#pragma unroll
  for (int e = 0; e < 8; ++e) {
    int idx = (t + e * 256) * 4;
    int d = idx >> 6;
    int kv0 = idx & 63;
    ushort4 o;
    o.x = T[d][kv0]; o.y = T[d][kv0 + 1]; o.z = T[d][kv0 + 2]; o.w = T[d][kv0 + 3];
    *reinterpret_cast<ushort4*>(Vt + ((size_t)h * HD + d) * KVL + kt * 64 + kv0) = o;
  }
}

// ---------------- flash attention ----------------
// grid (SEQ/64, NH), 256 thr. Wave w handles 16 q-rows. KVT=64.
#define KVT 64
__global__ __launch_bounds__(256, 2) void k_attn(
    const unsigned short* __restrict__ QKV,
    const unsigned short* __restrict__ Kb,
    const unsigned short* __restrict__ Vt,
    float* __restrict__ O) {
  __shared__ unsigned short Ks[KVT * HD];  // [64][128] swizzled
  __shared__ unsigned short Vs[HD * KVT];  // [128][64] swizzled
  __shared__ unsigned short Ps[4][16 * 72];
  const int tid = threadIdx.x, lane = tid & 63, wid = tid >> 6;
  const int h = blockIdx.y, qt = blockIdx.x;
  const int q0 = qt * 64 + wid * 16;

  short8 qf[4];
#pragma unroll
  for (int c = 0; c < 4; ++c)
    qf[c] = *reinterpret_cast<const short8*>(
        QKV + (size_t)(q0 + (lane & 15)) * W3H + h * HD + c * 32 + (lane >> 4) * 8);

  float m_r[4], l_r[4];
  f32x4 acc_o[8] = {};
#pragma unroll
  for (int r = 0; r < 4; ++r) { m_r[r] = -1e30f; l_r[r] = 0.f; }

  const char* Kh = (const char*)(Kb + (size_t)h * KVL * HD);
  const char* Vh = (const char*)(Vt + (size_t)h * HD * KVL);
  unsigned short* Pw = &Ps[wid][0];

  for (int kt = 0; kt < KVL / KVT; ++kt) {
    __syncthreads();
    // stage K [64][128] and Vt [128][64], XOR-swizzled via pre-swizzled global src
#pragma unroll
    for (int i = 0; i < 4; ++i) {
      int c = wid * 4 + i;
      int krow = c * 4 + (lane >> 4);
      int klcb = (16 * (lane & 15)) ^ ((krow & 7) << 4);
      GLOAD_LDS16(Kh + (size_t)(kt * KVT + krow) * 256 + klcb, (char*)Ks + c * 1024);
      int vrow = c * 8 + (lane >> 3);
      int vlcb = (16 * (lane & 7)) ^ ((vrow & 7) << 4);
      GLOAD_LDS16(Vh + (size_t)vrow * (KVL * 2) + (size_t)kt * (KVT * 2) + vlcb,
                  (char*)Vs + c * 1024);
    }
    __syncthreads();

    // S = Q K^T  (16q x 64kv per wave)
    f32x4 s[4] = {};
#pragma unroll
    for (int n = 0; n < 4; ++n) {
      int row = n * 16 + (lane & 15);
#pragma unroll
      for (int c = 0; c < 4; ++c) {
        int cb = (c * 32 + (lane >> 4) * 8) * 2;
        short8 kf = *reinterpret_cast<const short8*>(
            (const char*)Ks + row * 256 + (cb ^ ((row & 7) << 4)));
        s[n] = __builtin_amdgcn_mfma_f32_16x16x32_bf16(qf[c], kf, s[n], 0, 0, 0);
      }
    }

    // online softmax over this tile's 64 cols
    float p[4][4], tmax[4], rsum[4];
#pragma unroll
    for (int r = 0; r < 4; ++r) {
      float t0 = fmaxf(fmaxf(s[0][r], s[1][r]), fmaxf(s[2][r], s[3][r])) * ATTN_SCALE;
#pragma unroll
      for (int off = 1; off < 16; off <<= 1) t0 = fmaxf(t0, __shfl_xor(t0, off, 64));
      tmax[r] = t0;
    }
#pragma unroll
    for (int r = 0; r < 4; ++r) {
      float mn = fmaxf(m_r[r], tmax[r]);
      float alpha = __expf(m_r[r] - mn);
      float sum = 0.f;
#pragma unroll
      for (int n = 0; n < 4; ++n) {
        p[n][r] = __expf(s[n][r] * ATTN_SCALE - mn);
        sum += p[n][r];
      }
#pragma unroll
      for (int off = 1; off < 16; off <<= 1) sum += __shfl_xor(sum, off, 64);
      l_r[r] = l_r[r] * alpha + sum;
      m_r[r] = mn;
#pragma unroll
      for (int nd = 0; nd < 8; ++nd) acc_o[nd][r] *= alpha;
    }

    // P -> LDS (per-wave, padded to 72)
#pragma unroll
    for (int n = 0; n < 4; ++n)
#pragma unroll
      for (int r = 0; r < 4; ++r)
        Pw[((lane >> 4) * 4 + r) * 72 + n * 16 + (lane & 15)] = f2b(p[n][r]);

    // O += P V   (A = P [16][64], B = V [64][128] via Vt)
#pragma unroll
    for (int kc = 0; kc < 2; ++kc) {
      short8 pf = *reinterpret_cast<const short8*>(Pw + (lane & 15) * 72 + kc * 32 + (lane >> 4) * 8);
#pragma unroll
      for (int nd = 0; nd < 8; ++nd) {
        int row = nd * 16 + (lane & 15);
        int cb = kc * 64 + (lane >> 4) * 16;
        short8 vf = *reinterpret_cast<const short8*>(
            (const char*)Vs + row * 128 + (cb ^ ((row & 7) << 4)));
        acc_o[nd] = __builtin_amdgcn_mfma_f32_16x16x32_bf16(pf, vf, acc_o[nd], 0, 0, 0);
      }
    }
  }

  // epilogue: O[q][h*128+d] = acc / l
#pragma unroll
  for (int nd = 0; nd < 8; ++nd)
#pragma unroll
    for (int r = 0; r < 4; ++r)
      O[(size_t)(q0 + (lane >> 4) * 4 + r) * H_DIM + h * HD + nd * 16 + (lane & 15)] =
          acc_o[nd][r] / l_r[r];
}

extern "C" void kernel_launch(void* const* d_in, const int* in_sizes, int n_in,
                              void* d_out, int out_size, void* d_ws, size_t ws_size,
                              hipStream_t stream) {
  const float* X = (const float*)d_in[0];
  const float* W = (const float*)d_in[1];
  const float* cK = (const float*)d_in[2];
  const float* cV = (const float*)d_in[3];
  float* out = (float*)d_out;
  char* ws = (char*)d_ws;

  // ws layout (128 MB): Xb[0,8M) QKVb[8M,32M) Wb[32M,128M); Kb/Vt overlap Wb after GEMM
  unsigned short* Xb = (unsigned short*)(ws);
  unsigned short* QKVb = (unsigned short*)(ws + ((size_t)8 << 20));
  unsigned short* Wb = (unsigned short*)(ws + ((size_t)32 << 20));
  unsigned short* Kb = (unsigned short*)(ws + ((size_t)32 << 20));
  unsigned short* Vt = (unsigned short*)(ws + ((size_t)72 << 20));

  k_cvt<<<(SEQ * H_DIM / 4) / 256, 256, 0, stream>>>(X, Xb, SEQ * H_DIM / 4);
  k_cvt<<<(W3H * H_DIM / 4) / 256, 256, 0, stream>>>(W, Wb, W3H * H_DIM / 4);

  dim3 gg(W3H / BN, SEQ / BM);
  k_gemm_qkv<<<gg, 256, 0, stream>>>(Xb, Wb, QKVb);

  k_build_k<<<(NH * KVL * HD / 4) / 256, 256, 0, stream>>>(cK, QKVb, Kb);
  dim3 gv(KVL / 64, NH);
  k_build_vt<<<gv, 256, 0, stream>>>(cV, QKVb, Vt);

  dim3 ga(SEQ / 64, NH);
  k_attn<<<ga, 256, 0, stream>>>(QKVb, Kb, Vt, out);
}